// Round 13
// baseline (465.559 us; speedup 1.0000x reference)
//
#include <hip/hip_runtime.h>

// GAT node regressor: 3 GAT layers (HID=64, 4 heads x 16) + linear head.
// CSR-by-dst built once per call via bucketed counting sort. Per layer:
//   k_mgemm: xh = h@W on MATRIX CORES via bf16 hi/lo split (fp32 emulation:
//            hh*wh + hh*wl + lo*wh, fp32 MFMA accumulate). Wave = 16 nodes x
//            64 cols, K-step 32, no LDS; W pre-packed into B-fragment order
//            (L1-resident). Fused al_s/al_d logits via intra-quad shuffles.
//   k_agg  : wave-per-dst-node gather with INLINE edge logits (lane=edge
//            computes all 4 heads' pe -> head-transposed LDS stash), then
//            4-group (16 gathers in flight) accumulate with dual acc/z chains.
//            Layer 2 fuses h@out_w via shuffle.
// Launch trims: hipMemsetAsync replaces k_zero; k_wprep merged into k_bhist.

#define NBMAX 512   // max dst buckets (dst>>8); N=100K -> 391
#define SCHUNK 4096 // edges per k_bscatter block
#define BCAP 8192   // per-bucket LDS src capacity in k_bfinal (avg 4096)

typedef __attribute__((ext_vector_type(8))) short bf16x8;
typedef __attribute__((ext_vector_type(4))) float f32x4;

__device__ inline unsigned short bf16_rtn(float x) {
    union { float f; unsigned u; } a; a.f = x;
    return (unsigned short)((a.u + 0x7FFFu + ((a.u >> 16) & 1u)) >> 16);
}
__device__ inline float bf16_to_f(unsigned short s) {
    union { unsigned u; float f; } b; b.u = ((unsigned)s) << 16;
    return b.f;
}

// blocks 0..7: pack W into MFMA B-fragment hi/lo bf16; blocks 8..263: bhist.
__global__ __launch_bounds__(256) void k_bhist_wprep(
        const int* __restrict__ dst, int* __restrict__ bhist, int e,
        const float* __restrict__ w0, const float* __restrict__ w1, const float* __restrict__ w2,
        unsigned short* __restrict__ p0h, unsigned short* __restrict__ p0l,
        unsigned short* __restrict__ p1h, unsigned short* __restrict__ p1l,
        unsigned short* __restrict__ p2h, unsigned short* __restrict__ p2l) {
    int t = threadIdx.x;
    if (blockIdx.x < 8) {
        int g = blockIdx.x * 256 + t;
        const float* W;
        unsigned short *ph, *pl;
        int idx;
        if (g < 1024) { W = w0; ph = p0h; pl = p0l; idx = g; }          // D=128
        else if (g < 1536) { W = w1; ph = p1h; pl = p1l; idx = g - 1024; }
        else if (g < 2048) { W = w2; ph = p2h; pl = p2l; idx = g - 1536; }
        else return;
        int ko = idx >> 6, nn = idx & 63;
#pragma unroll
        for (int j = 0; j < 8; ++j) {
            float w = W[(size_t)(ko * 8 + j) * 64 + nn];
            unsigned short hb = bf16_rtn(w);
            ph[(size_t)idx * 8 + j] = hb;
            pl[(size_t)idx * 8 + j] = bf16_rtn(w - bf16_to_f(hb));
        }
        return;
    }
    __shared__ unsigned int h[NBMAX];
    h[t] = 0;
    h[t + 256] = 0;
    __syncthreads();
    int bid = blockIdx.x - 8;
    for (int i = bid * 256 + t; i < e; i += 256 * 256)
        atomicAdd(&h[dst[i] >> 8], 1u);
    __syncthreads();
    if (h[t]) atomicAdd(&bhist[t], (int)h[t]);
    if (h[t + 256]) atomicAdd(&bhist[t + 256], (int)h[t + 256]);
}

__global__ __launch_bounds__(512) void k_bscan(const int* __restrict__ bhist, int* __restrict__ boffs,
                                               int* __restrict__ bfill, int nb, int e) {
    __shared__ int s[NBMAX];
    int t = threadIdx.x;
    int v = (t < nb) ? bhist[t] : 0;
    s[t] = v;
    __syncthreads();
    for (int o = 1; o < 512; o <<= 1) {
        int add = (t >= o) ? s[t - o] : 0;
        __syncthreads();
        s[t] += add;
        __syncthreads();
    }
    boffs[t] = s[t] - v;  // exclusive
    if (t == 511) boffs[512] = s[511];
    bfill[t] = 0;
}

// Block-local counting sort of a 4096-edge chunk by dst>>8, then streamed
// writes of sorted runs. Packs src (17b) | (dst&255)<<24 into 4B.
__global__ __launch_bounds__(512) void k_bscatter(const int* __restrict__ src, const int* __restrict__ dst,
                                                  const int* __restrict__ boffs, int* __restrict__ bfill,
                                                  unsigned int* __restrict__ edata, int e) {
    __shared__ unsigned int hist[NBMAX];   // counts, then cursor
    __shared__ unsigned int loc[NBMAX];    // local exclusive offsets
    __shared__ int gbase[NBMAX];
    __shared__ unsigned int stmp[NBMAX];
    __shared__ unsigned int sortbuf[SCHUNK];
    __shared__ int posbuf[SCHUNK];
    int t = threadIdx.x;
    int i0 = blockIdx.x * SCHUNK;
    int cnt = min(SCHUNK, e - i0);
    hist[t] = 0;
    __syncthreads();
    for (int j = t; j < cnt; j += 512) atomicAdd(&hist[dst[i0 + j] >> 8], 1u);
    __syncthreads();
    unsigned int v = hist[t];
    stmp[t] = v;
    __syncthreads();
    for (int o = 1; o < 512; o <<= 1) {
        unsigned int add = (t >= o) ? stmp[t - o] : 0;
        __syncthreads();
        stmp[t] += add;
        __syncthreads();
    }
    loc[t] = stmp[t] - v;
    int gb = 0;
    if (v > 0) gb = atomicAdd(&bfill[t], (int)v);  // reserve contiguous run in bucket t
    gbase[t] = boffs[t] + gb - (int)loc[t];
    hist[t] = loc[t];  // cursor
    __syncthreads();
    for (int j = t; j < cnt; j += 512) {
        int d = dst[i0 + j];
        int s = src[i0 + j];
        int b = d >> 8;
        unsigned int p = atomicAdd(&hist[b], 1u);
        sortbuf[p] = (unsigned int)s | ((unsigned int)(d & 255) << 24);
        posbuf[p] = gbase[b] + (int)p;
    }
    __syncthreads();
    for (int j = t; j < cnt; j += 512) edata[posbuf[j]] = sortbuf[j];
}

// One block per bucket: 256-bin counting sort by local dst; coalesced offs
// and ssrc output.
__global__ __launch_bounds__(256) void k_bfinal(const unsigned int* __restrict__ edata,
                                                const int* __restrict__ boffs, int* __restrict__ offs,
                                                int* __restrict__ ssrc, int n, int nb) {
    __shared__ unsigned int hist[256];
    __shared__ unsigned int stmp[256];
    __shared__ unsigned int loc[256];
    __shared__ unsigned int srcbuf[BCAP];
    int b = blockIdx.x;
    int t = threadIdx.x;
    int e0 = boffs[b], e1 = boffs[b + 1];
    int cnt = e1 - e0;
    hist[t] = 0;
    __syncthreads();
    for (int j = t; j < cnt; j += 256) atomicAdd(&hist[edata[e0 + j] >> 24], 1u);
    __syncthreads();
    unsigned int v = hist[t];
    stmp[t] = v;
    __syncthreads();
    for (int o = 1; o < 256; o <<= 1) {
        unsigned int add = (t >= o) ? stmp[t - o] : 0;
        __syncthreads();
        stmp[t] += add;
        __syncthreads();
    }
    loc[t] = stmp[t] - v;
    int node = b * 256 + t;
    if (node < n) offs[node] = e0 + (int)loc[t];
    if (b == nb - 1 && t == 0) offs[n] = e1;
    hist[t] = loc[t];  // cursor
    __syncthreads();
    if (cnt <= BCAP) {
        for (int j = t; j < cnt; j += 256) {
            unsigned int p = edata[e0 + j];
            unsigned int pos = atomicAdd(&hist[p >> 24], 1u);
            srcbuf[pos] = p & 0xFFFFFFu;
        }
        __syncthreads();
        for (int j = t; j < cnt; j += 256) ssrc[e0 + j] = (int)srcbuf[j];
    } else {  // safety fallback (never hit for Poisson(4096) buckets)
        for (int j = t; j < cnt; j += 256) {
            unsigned int p = edata[e0 + j];
            unsigned int pos = atomicAdd(&hist[p >> 24], 1u);
            ssrc[e0 + (int)pos] = (int)(p & 0xFFFFFFu);
        }
    }
}

// xh = h @ W via MFMA, fused attention logits. Wave = 16 nodes x 64 cols.
// A frag: A[m=lane&15][k=quad*8+j]; B pre-packed mirror; C/D: col=lane&15,
// row=quad*4+reg. 3 MFMAs per (K-step, N-tile) = hi/lo fp32 emulation.
template <int D_IN>
__global__ __launch_bounds__(256) void k_mgemm(const float* __restrict__ h,
                                               const unsigned short* __restrict__ wph,
                                               const unsigned short* __restrict__ wpl,
                                               const float* __restrict__ asrc, const float* __restrict__ adst,
                                               float* __restrict__ xh, float* __restrict__ als,
                                               float* __restrict__ ald, int n) {
    int t = threadIdx.x;
    int wv = t >> 6, lane = t & 63;
    int quad = lane >> 4, l16 = lane & 15;
    int m0 = blockIdx.x * 64 + wv * 16;
    int node_a = m0 + l16;
    int mm = min(node_a, n - 1);
    const float* hrow = h + (size_t)mm * D_IN + quad * 8;

    f32x4 acc[4];
#pragma unroll
    for (int i = 0; i < 4; ++i) acc[i] = (f32x4){0.f, 0.f, 0.f, 0.f};

    constexpr int KSTEPS = D_IN / 32;
#pragma unroll
    for (int s = 0; s < KSTEPS; ++s) {
        float4 a0 = *(const float4*)(hrow + s * 32);
        float4 a1 = *(const float4*)(hrow + s * 32 + 4);
        float av[8] = {a0.x, a0.y, a0.z, a0.w, a1.x, a1.y, a1.z, a1.w};
        bf16x8 ahi, alo;
#pragma unroll
        for (int j = 0; j < 8; ++j) {
            unsigned short hb = bf16_rtn(av[j]);
            ahi[j] = (short)hb;
            alo[j] = (short)bf16_rtn(av[j] - bf16_to_f(hb));
        }
        const unsigned short* bbase = wph + ((size_t)((s * 4 + quad) * 64 + l16)) * 8;
        const unsigned short* bbasel = wpl + ((size_t)((s * 4 + quad) * 64 + l16)) * 8;
#pragma unroll
        for (int nt = 0; nt < 4; ++nt) {
            bf16x8 bhi = *(const bf16x8*)(bbase + (size_t)nt * 16 * 8);
            bf16x8 blo = *(const bf16x8*)(bbasel + (size_t)nt * 16 * 8);
            acc[nt] = __builtin_amdgcn_mfma_f32_16x16x32_bf16(ahi, bhi, acc[nt], 0, 0, 0);
            acc[nt] = __builtin_amdgcn_mfma_f32_16x16x32_bf16(ahi, blo, acc[nt], 0, 0, 0);
            acc[nt] = __builtin_amdgcn_mfma_f32_16x16x32_bf16(alo, bhi, acc[nt], 0, 0, 0);
        }
    }
#pragma unroll
    for (int nt = 0; nt < 4; ++nt) {
        float as_l = asrc[nt * 16 + l16];
        float ad_l = adst[nt * 16 + l16];
#pragma unroll
        for (int r = 0; r < 4; ++r) {
            int node = m0 + quad * 4 + r;
            float c = acc[nt][r];
            if (node < n) xh[(size_t)node * 64 + nt * 16 + l16] = c;
            float ps = c * as_l, pd = c * ad_l;
            ps += __shfl_xor(ps, 1, 64); pd += __shfl_xor(pd, 1, 64);
            ps += __shfl_xor(ps, 2, 64); pd += __shfl_xor(pd, 2, 64);
            ps += __shfl_xor(ps, 4, 64); pd += __shfl_xor(pd, 4, 64);
            ps += __shfl_xor(ps, 8, 64); pd += __shfl_xor(pd, 8, 64);
            if (l16 == 0 && node < n) {
                als[node * 4 + nt] = ps;
                ald[node * 4 + nt] = pd;
            }
        }
    }
}

__device__ inline float4 lrelu4(float4 v) {
    float4 r;
    r.x = v.x >= 0.f ? v.x : 0.2f * v.x;
    r.y = v.y >= 0.f ? v.y : 0.2f * v.y;
    r.z = v.z >= 0.f ? v.z : 0.2f * v.z;
    r.w = v.w >= 0.f ? v.w : 0.2f * v.w;
    return r;
}

// One wave per destination node; lane = feature column (head = lane>>4).
// Chunk phase (lane=edge): gather als4[u] (L2-resident), compute all 4 heads'
// pe = exp(lrelu(als[u]+ald[v]) - m_v) inline (single pass; m_v = self-logit,
// algebraically identical to ref's max-subtraction); stash u as row BYTE
// offset + pe transposed [head][edge] in LDS (all 64 lanes write; pad u=v,
// pe=0 via alu=-1e30 -> exp=0). Accumulate: 4-group unroll = 16 row-gathers
// in flight, dual acc/z chains; z redundant per lane (no shuffle-reduce).
__global__ __launch_bounds__(256) void k_agg(const float* __restrict__ xh, const float* __restrict__ als,
                                             const float* __restrict__ ald, const int* __restrict__ offs,
                                             const int* __restrict__ ssrc, const float* __restrict__ bias,
                                             float* __restrict__ hout, const float* __restrict__ outw,
                                             const float* __restrict__ outb, float* __restrict__ fout, int n) {
    __shared__ int s_u[4][64];
    __shared__ float s_pe[4][4][64];  // [wslot][head][edge]
    int wslot = threadIdx.x >> 6;
    int lane = threadIdx.x & 63;
    int v = (blockIdx.x * 256 + threadIdx.x) >> 6;
    if (v >= n) return;
    int head = lane >> 4;
    int* ub = s_u[wslot];
    float* per = s_pe[wslot][head];      // read row for my head
    float* pew = &s_pe[wslot][0][lane];  // write base, stride 64 per head

    int start = offs[v], end = offs[v + 1];
    float4 ald4 = *(const float4*)(ald + 4 * (size_t)v);
    float4 als4v = *(const float4*)(als + 4 * (size_t)v);
    float4 m4 = lrelu4(make_float4(als4v.x + ald4.x, als4v.y + ald4.y, als4v.z + ald4.z, als4v.w + ald4.w));

    const char* xl = (const char*)(xh + lane);      // lane column folded into base
    float acc0 = *(const float*)(xl + ((size_t)(unsigned)v << 8));  // self, pe=1
    float acc1 = 0.f;
    float zs0 = 0.f, zs1 = 0.f;

    for (int s0 = start; s0 < end; s0 += 64) {
        int cnt = min(64, end - s0);
        bool act = lane < cnt;
        int u = v;
        float4 alu = make_float4(-1e30f, -1e30f, -1e30f, -1e30f);
        if (act) {
            u = ssrc[s0 + lane];
            alu = *(const float4*)(als + 4 * (size_t)u);
        }
        float4 e4 = lrelu4(make_float4(alu.x + ald4.x, alu.y + ald4.y, alu.z + ald4.z, alu.w + ald4.w));
        float4 pe;
        pe.x = __expf(e4.x - m4.x);  // inactive lanes -> exp(-huge) = 0
        pe.y = __expf(e4.y - m4.y);
        pe.z = __expf(e4.z - m4.z);
        pe.w = __expf(e4.w - m4.w);
        ub[lane] = u << 8;   // row byte offset; pad lanes point at v (pe=0)
        pew[0] = pe.x;       // transposed stash: bank stride 64 -> 2-way, free
        pew[64] = pe.y;
        pew[128] = pe.z;
        pew[192] = pe.w;
        // same-wave LDS RAW (in-order DS unit), no barrier needed
        int ngp = (cnt + 3) >> 2;
        int g = 0;
        for (; g + 4 <= ngp; g += 4) {
            int4 uu0 = *(const int4*)&ub[g * 4];
            int4 uu1 = *(const int4*)&ub[g * 4 + 4];
            int4 uu2 = *(const int4*)&ub[g * 4 + 8];
            int4 uu3 = *(const int4*)&ub[g * 4 + 12];
            float4 pp0 = *(const float4*)&per[g * 4];
            float4 pp1 = *(const float4*)&per[g * 4 + 4];
            float4 pp2 = *(const float4*)&per[g * 4 + 8];
            float4 pp3 = *(const float4*)&per[g * 4 + 12];
            float x0 = *(const float*)(xl + (size_t)(unsigned)uu0.x);
            float x1 = *(const float*)(xl + (size_t)(unsigned)uu0.y);
            float x2 = *(const float*)(xl + (size_t)(unsigned)uu0.z);
            float x3 = *(const float*)(xl + (size_t)(unsigned)uu0.w);
            float x4 = *(const float*)(xl + (size_t)(unsigned)uu1.x);
            float x5 = *(const float*)(xl + (size_t)(unsigned)uu1.y);
            float x6 = *(const float*)(xl + (size_t)(unsigned)uu1.z);
            float x7 = *(const float*)(xl + (size_t)(unsigned)uu1.w);
            float x8 = *(const float*)(xl + (size_t)(unsigned)uu2.x);
            float x9 = *(const float*)(xl + (size_t)(unsigned)uu2.y);
            float xa = *(const float*)(xl + (size_t)(unsigned)uu2.z);
            float xb = *(const float*)(xl + (size_t)(unsigned)uu2.w);
            float xc = *(const float*)(xl + (size_t)(unsigned)uu3.x);
            float xd = *(const float*)(xl + (size_t)(unsigned)uu3.y);
            float xe = *(const float*)(xl + (size_t)(unsigned)uu3.z);
            float xf = *(const float*)(xl + (size_t)(unsigned)uu3.w);
            zs0 += (pp0.x + pp0.y) + (pp0.z + pp0.w) + (pp2.x + pp2.y) + (pp2.z + pp2.w);
            zs1 += (pp1.x + pp1.y) + (pp1.z + pp1.w) + (pp3.x + pp3.y) + (pp3.z + pp3.w);
            acc0 += pp0.x * x0; acc0 += pp0.y * x1; acc0 += pp0.z * x2; acc0 += pp0.w * x3;
            acc1 += pp1.x * x4; acc1 += pp1.y * x5; acc1 += pp1.z * x6; acc1 += pp1.w * x7;
            acc0 += pp2.x * x8; acc0 += pp2.y * x9; acc0 += pp2.z * xa; acc0 += pp2.w * xb;
            acc1 += pp3.x * xc; acc1 += pp3.y * xd; acc1 += pp3.z * xe; acc1 += pp3.w * xf;
        }
        for (; g < ngp; ++g) {
            int4 uu = *(const int4*)&ub[g * 4];
            float4 pp = *(const float4*)&per[g * 4];
            float x0 = *(const float*)(xl + (size_t)(unsigned)uu.x);
            float x1 = *(const float*)(xl + (size_t)(unsigned)uu.y);
            float x2 = *(const float*)(xl + (size_t)(unsigned)uu.z);
            float x3 = *(const float*)(xl + (size_t)(unsigned)uu.w);
            zs0 += (pp.x + pp.y) + (pp.z + pp.w);
            acc0 += pp.x * x0; acc0 += pp.y * x1; acc0 += pp.z * x2; acc0 += pp.w * x3;
        }
    }
    float z = 1.f + zs0 + zs1;  // +1 = self edge
    float o = (acc0 + acc1) / (z + 1e-16f) + bias[lane];
    o = fmaxf(o, 0.f);
    if (outw) {
        float tsum = o * outw[lane];
#pragma unroll
        for (int d = 32; d; d >>= 1) tsum += __shfl_down(tsum, d, 64);
        if (lane == 0) fout[v] = tsum + outb[0];
    } else {
        hout[((size_t)v << 6) + lane] = o;
    }
}

extern "C" void kernel_launch(void* const* d_in, const int* in_sizes, int n_in,
                              void* d_out, int out_size, void* d_ws, size_t ws_size,
                              hipStream_t stream) {
    const float* x = (const float*)d_in[0];
    const int* ei = (const int*)d_in[1];
    const float* w[3] = {(const float*)d_in[2], (const float*)d_in[6], (const float*)d_in[10]};
    const float* as[3] = {(const float*)d_in[3], (const float*)d_in[7], (const float*)d_in[11]};
    const float* ad[3] = {(const float*)d_in[4], (const float*)d_in[8], (const float*)d_in[12]};
    const float* b[3] = {(const float*)d_in[5], (const float*)d_in[9], (const float*)d_in[13]};
    const float* outw = (const float*)d_in[14];
    const float* outb = (const float*)d_in[15];

    const int N = in_sizes[0] / 128;
    const int E = in_sizes[1] / 2;
    const int* src = ei;
    const int* dst = ei + E;
    const int NB = (N + 255) / 256;  // 391 <= NBMAX

    char* ws = (char*)d_ws;
    auto alloc = [&](size_t bytes) -> void* {
        void* p = (void*)ws;
        ws += (bytes + 255) & ~(size_t)255;
        return p;
    };
    int* bhist = (int*)alloc(NBMAX * 4);
    int* boffs = (int*)alloc((NBMAX + 1) * 4);
    int* bfill = (int*)alloc(NBMAX * 4);
    int* offs = (int*)alloc((size_t)(N + 1) * 4);
    int* ssrc = (int*)alloc((size_t)E * 4);
    float* xh = (float*)alloc((size_t)N * 64 * 4);
    float* hbuf = (float*)alloc((size_t)N * 64 * 4);
    float* als = (float*)alloc((size_t)N * 4 * 4);
    float* ald = (float*)alloc((size_t)N * 4 * 4);
    unsigned short* p0h = (unsigned short*)alloc(8192 * 2);
    unsigned short* p0l = (unsigned short*)alloc(8192 * 2);
    unsigned short* p1h = (unsigned short*)alloc(4096 * 2);
    unsigned short* p1l = (unsigned short*)alloc(4096 * 2);
    unsigned short* p2h = (unsigned short*)alloc(4096 * 2);
    unsigned short* p2l = (unsigned short*)alloc(4096 * 2);
    // edata (E*4B) aliases xh (N*256B): dead before the first k_mgemm writes xh.
    unsigned int* edata = (unsigned int*)xh;

    hipMemsetAsync(bhist, 0, NBMAX * 4, stream);
    k_bhist_wprep<<<264, 256, 0, stream>>>(dst, bhist, E, w[0], w[1], w[2],
                                           p0h, p0l, p1h, p1l, p2h, p2l);
    k_bscan<<<1, 512, 0, stream>>>(bhist, boffs, bfill, NB, E);
    k_bscatter<<<(E + SCHUNK - 1) / SCHUNK, 512, 0, stream>>>(src, dst, boffs, bfill, edata, E);
    k_bfinal<<<NB, 256, 0, stream>>>(edata, boffs, offs, ssrc, N, NB);

    const int gblocks = (N + 63) / 64;
    const int ablocks = (N + 3) / 4;

    k_mgemm<128><<<gblocks, 256, 0, stream>>>(x, p0h, p0l, as[0], ad[0], xh, als, ald, N);
    k_agg<<<ablocks, 256, 0, stream>>>(xh, als, ald, offs, ssrc, b[0], hbuf, nullptr, nullptr, nullptr, N);
    k_mgemm<64><<<gblocks, 256, 0, stream>>>(hbuf, p1h, p1l, as[1], ad[1], xh, als, ald, N);
    k_agg<<<ablocks, 256, 0, stream>>>(xh, als, ald, offs, ssrc, b[1], hbuf, nullptr, nullptr, nullptr, N);
    k_mgemm<64><<<gblocks, 256, 0, stream>>>(hbuf, p2h, p2l, as[2], ad[2], xh, als, ald, N);
    k_agg<<<ablocks, 256, 0, stream>>>(xh, als, ald, offs, ssrc, b[2], nullptr, outw, outb, (float*)d_out, N);
}